// Round 20
// baseline (60.992 us; speedup 1.0000x reference)
//
#include <hip/hip_runtime.h>
#include <hip/hip_bf16.h>

typedef __bf16 bf16x8 __attribute__((ext_vector_type(8)));
typedef __bf16 bf16x4 __attribute__((ext_vector_type(4)));
typedef __bf16 bf16x2 __attribute__((ext_vector_type(2)));
typedef float  f32x4  __attribute__((ext_vector_type(4)));
typedef float  f32x2  __attribute__((ext_vector_type(2)));

constexpr int kD  = 512;
constexpr int kBD = 64;
constexpr int kN  = 4096;
constexpr int kB  = 8;

// Prep: Wbk/Wbv fp32 -> bf16 ws images (blocks 0..31); block 32 zeroes S.
__global__ __launch_bounds__(256)
void lbm_prep(const float* __restrict__ Wbk, const float* __restrict__ Wbv,
              __bf16* __restrict__ wsk, __bf16* __restrict__ wsv,
              float* __restrict__ S)
{
    const int bid = blockIdx.x, t = threadIdx.x;
    if (bid < 32) {
        int i = (bid * 256 + t) * 4;
        float4 a = *(const float4*)(Wbk + i);
        float4 b = *(const float4*)(Wbv + i);
        bf16x4 ka, vb;
        ka[0]=(__bf16)a.x; ka[1]=(__bf16)a.y; ka[2]=(__bf16)a.z; ka[3]=(__bf16)a.w;
        vb[0]=(__bf16)b.x; vb[1]=(__bf16)b.y; vb[2]=(__bf16)b.z; vb[3]=(__bf16)b.w;
        *(bf16x4*)(wsk + i) = ka;
        *(bf16x4*)(wsv + i) = vb;
    } else {
        S[t * 2] = 0.f; S[t * 2 + 1] = 0.f;
    }
}

// Pass 1: kp[row,j] = keys[row,:].Wbk[j,:] + bbk[j]  (arr = bid&1 picks K/V).
// R17's refcheck'd engine with 16-BYTE data requests (the one untested lever;
// request-rate model: chip saturates at ~2 req/ns/CU independent of size).
// Phase = 64 rows x 64 d (16 KB), one dwordx4 per thread per phase; data
// requests 16.8M -> 8.4M; sequential phases per block-slot 32 -> 16.
// Wave roles: chunk(4) x jt(4), full d per wave -> no dgrp split, no red
// buffer, ONE barrier per phase. LDS = 64K weights + 16K dbuf = 80 KB ->
// 2 blocks/CU. 3-deep counted vmcnt (never drains), lgkmcnt-only barriers.
__global__ __launch_bounds__(1024, 8)
void lbm_proj(const float* __restrict__ keys, const float* __restrict__ values,
              const __bf16* __restrict__ wsk, const __bf16* __restrict__ wsv,
              const float* __restrict__ bbk,  const float* __restrict__ bbv,
              __bf16* __restrict__ kp,        __bf16* __restrict__ vp)
{
    __shared__ __align__(16) __bf16 ldsW[kBD * kD];    // swizzled weights, 64 KB
    __shared__ __align__(16) __bf16 ldsD[2][64 * 64];  // data dbuf bf16, 16 KB

    const int tid = threadIdx.x;
    const int w   = tid >> 6;
    const int ln  = tid & 63;
    const int l15 = ln & 15;
    const int lhi = ln >> 4;
    const int sw7 = l15 & 7;
    const int chunk = w & 3;            // 16-row chunk of the staged 64 rows
    const int jt    = w >> 2;           // j-tile

    const int bid = blockIdx.x;
    const int arr = bid & 1;
    const int t0  = bid >> 1;                       // 0..255
    const int swz = (t0 & 7) * 32 + (t0 >> 3);      // XCD-bijective (256 = 8*32)
    const int rows0 = swz * 128;                    // 2 tiles x 64 rows

    const float*  src  = arr ? values : keys;
    const __bf16* wsrc = arr ? wsv    : wsk;
    const float*  bsrc = arr ? bbv    : bbk;
    __bf16*       dst  = arr ? vp     : kp;

    // data staging: thread owns 4 floats (16 B)/phase; 16 threads cover a row
    const int srow = tid >> 4;                      // 0..63
    const float* sbase = src + (size_t)(rows0 + srow) * kD + (tid & 15) * 4;
    // swizzled LDS write: granule g = (tid&15)>>1, half = tid&1
    const int wel = srow * 64 + (((((tid & 15) >> 1)) ^ (srow & 7)) << 3) + (tid & 1) * 4;

#define LOADD(sl, t_, dph_)                                                   \
    asm volatile("global_load_dwordx4 %0, %1, off offset:%c2"                 \
                 : "=v"(sl) : "v"(sbase + (t_) * (64 * kD)), "i"((dph_) * 256));
#define WAITD(sl, n)                                                          \
    asm volatile("s_waitcnt vmcnt(%c1)" : "+v"(sl) : "i"(n));

    f32x4 s0, s1, s2;
#define SLOT(q) ((q) % 3 == 0 ? s0 : ((q) % 3 == 1 ? s1 : s2))

    LOADD(s0, 0, 0) LOADD(s1, 0, 1) LOADD(s2, 0, 2)   // data loads FIRST (oldest)

    // ---- weight staging: 64KB bf16 image -> XOR-swizzled LDS ----
    #pragma unroll
    for (int i = 0; i < 4; ++i) {
        int G = i * 1024 + tid;              // granule16 0..4095
        int j = G >> 6, c = G & 63;
        *(bf16x8*)&ldsW[j * kD + ((c ^ (j & 7)) << 3)] = *(const bf16x8*)(wsrc + G * 8);
    }
    const float bias = bsrc[jt * 16 + l15];

    // phase-0 write (vmcnt(2): everything older than {s1,s2} retired -> s0 done)
    WAITD(s0, 2)
    { bf16x4 t4; t4[0] = (__bf16)s0[0]; t4[1] = (__bf16)s0[1];
      t4[2] = (__bf16)s0[2]; t4[3] = (__bf16)s0[3];
      *(bf16x4*)&ldsD[0][wel] = t4; }
    __syncthreads();   // one-time prologue drain (weights + buf0 resident)

    f32x4 acc  = {0.f, 0.f, 0.f, 0.f};
    f32x4 res0 = {0.f, 0.f, 0.f, 0.f};   // tile 0 result
    f32x4 res1 = {0.f, 0.f, 0.f, 0.f};   // tile 1 result

    // phase p (0..15): tile = p>>3, d-phase pp = p&7.
    // [issue p+3] [2 MFMAs, all waves] [wait p+1, cvt+write] [barrier]
    // tile end (pp==7): acc complete over d=512 -> res, reset. No 2nd barrier.
#define PHASE(p_, waitn_)                                                     \
    {                                                                         \
        if ((p_) + 3 < 16) { LOADD(SLOT((p_) + 3), (((p_) + 3) >> 3), (((p_) + 3) & 7)) } \
        _Pragma("unroll")                                                     \
        for (int ks = 0; ks < 2; ++ks) {                                      \
            bf16x8 af = *(const bf16x8*)&ldsD[(p_) & 1]                       \
                [(chunk * 16 + l15) * 64 + (((ks * 4 + lhi) ^ sw7) << 3)];    \
            bf16x8 wf = *(const bf16x8*)&ldsW                                 \
                [(jt * 16 + l15) * kD + (((((p_) & 7) * 8 + ks * 4 + lhi) ^ sw7) << 3)]; \
            acc = __builtin_amdgcn_mfma_f32_16x16x32_bf16(af, wf, acc, 0, 0, 0); \
        }                                                                     \
        if ((p_) + 1 < 16) {                                                  \
            WAITD(SLOT((p_) + 1), waitn_)                                     \
            bf16x4 t4; t4[0] = (__bf16)SLOT((p_) + 1)[0];                     \
            t4[1] = (__bf16)SLOT((p_) + 1)[1];                                \
            t4[2] = (__bf16)SLOT((p_) + 1)[2];                                \
            t4[3] = (__bf16)SLOT((p_) + 1)[3];                                \
            *(bf16x4*)&ldsD[((p_) + 1) & 1][wel] = t4;                        \
        }                                                                     \
        asm volatile("s_waitcnt lgkmcnt(0)" ::: "memory");                    \
        __builtin_amdgcn_s_barrier();                                         \
        if (((p_) & 7) == 7) {                                                \
            _Pragma("unroll")                                                 \
            for (int i = 0; i < 4; ++i) {                                     \
                float v = acc[i] + bias;                                      \
                if (((p_) >> 3) == 0) res0[i] = v; else res1[i] = v;          \
            }                                                                 \
            acc[0] = 0.f; acc[1] = 0.f; acc[2] = 0.f; acc[3] = 0.f;           \
        }                                                                     \
    }

    PHASE(0, 2)  PHASE(1, 2)  PHASE(2, 2)  PHASE(3, 2)
    PHASE(4, 2)  PHASE(5, 2)  PHASE(6, 2)  PHASE(7, 2)
    PHASE(8, 2)  PHASE(9, 2)  PHASE(10, 2) PHASE(11, 2)
    PHASE(12, 2) PHASE(13, 1) PHASE(14, 0) PHASE(15, 0)
#undef PHASE
#undef SLOT
#undef LOADD
#undef WAITD

    // store phase: each wave owns rows chunk*16 + (lhi*4..+3), cols jt*16+l15
    #pragma unroll
    for (int i = 0; i < 4; ++i) {
        dst[(size_t)(rows0 + chunk * 16 + lhi * 4 + i) * kBD
            + jt * 16 + l15] = (__bf16)res0[i];
        dst[(size_t)(rows0 + 64 + chunk * 16 + lhi * 4 + i) * kBD
            + jt * 16 + l15] = (__bf16)res1[i];
    }
}

// Pass 2: S[b,j] = sum_rows kp[row,j] * vp[row,j].  512 blocks x 64 rows, bf16x4.
__global__ __launch_bounds__(256)
void lbm_comb(const __bf16* __restrict__ kp, const __bf16* __restrict__ vp,
              float* __restrict__ S)
{
    const int t  = threadIdx.x;
    const int j4 = t & 15;          // 16 x bf16x4 = 64 j
    const int rg = t >> 4;          // 16 row-groups of 4 rows
    const size_t r0 = (size_t)blockIdx.x * 64 + rg * 4;
    const bf16x4* kp4 = (const bf16x4*)kp;
    const bf16x4* vp4 = (const bf16x4*)vp;
    f32x4 acc = {0.f, 0.f, 0.f, 0.f};
    #pragma unroll
    for (int r = 0; r < 4; ++r) {
        size_t idx = (r0 + r) * 16 + j4;
        bf16x4 a = kp4[idx], b = vp4[idx];
        acc[0] += (float)a[0] * (float)b[0];
        acc[1] += (float)a[1] * (float)b[1];
        acc[2] += (float)a[2] * (float)b[2];
        acc[3] += (float)a[3] * (float)b[3];
    }
    __shared__ f32x4 red[16][16];
    red[rg][j4] = acc;
    __syncthreads();
    if (t < 16) {
        f32x4 s = {0.f, 0.f, 0.f, 0.f};
        #pragma unroll
        for (int g = 0; g < 16; ++g) {
            f32x4 v = red[g][t];
            s[0] += v[0]; s[1] += v[1]; s[2] += v[2]; s[3] += v[3];
        }
        int b = (blockIdx.x * 64) >> 12;   // / kN
        atomicAdd(&S[b * kBD + t * 4 + 0], s[0]);
        atomicAdd(&S[b * kBD + t * 4 + 1], s[1]);
        atomicAdd(&S[b * kBD + t * 4 + 2], s[2]);
        atomicAdd(&S[b * kBD + t * 4 + 3], s[3]);
    }
}

// Fused tail: 64 blocks; each block redundantly computes S->Bsum->ms->ext->LN
// for its batch b, then its 64-wide slice of out = normed.Wo^T + bo.
__global__ __launch_bounds__(256)
void lbm_tail(const float* __restrict__ S,    const float* __restrict__ query,
              const float* __restrict__ Wbc,  const float* __restrict__ bbc,
              const float* __restrict__ Wuq,  const float* __restrict__ buq,
              const float* __restrict__ Wue,  const float* __restrict__ bue,
              const float* __restrict__ ln_g, const float* __restrict__ ln_b,
              const float* __restrict__ Wo,   const float* __restrict__ bo,
              float* __restrict__ out)
{
    const int b = blockIdx.x >> 3;
    const int s = blockIdx.x & 7;
    const int t = threadIdx.x;

    __shared__ float shS[kBD];
    __shared__ float shB[kD];
    __shared__ float shMs[kBD];
    __shared__ float shN[kD];
    __shared__ float redT[4][kBD];
    __shared__ float redQ[4][kBD];
    __shared__ float redLN[8];
    __shared__ float s_mu, s_rs;

    if (t < kBD) shS[t] = S[b * kBD + t];
    __syncthreads();

    for (int d = t; d < kD; d += 256) {
        const float4* wr = (const float4*)(Wbc + d * kBD);
        float acc = 0.f;
        #pragma unroll
        for (int q4 = 0; q4 < 16; ++q4) {
            float4 w = wr[q4];
            acc += w.x * shS[q4*4+0] + w.y * shS[q4*4+1]
                 + w.z * shS[q4*4+2] + w.w * shS[q4*4+3];
        }
        shB[d] = acc + (float)kN * bbc[d];
    }
    __syncthreads();

    {
        const int jj = t & 63, qq = t >> 6;
        const float4* wr = (const float4*)(Wuq + jj * kD + qq * 128);
        const float4* qr = (const float4*)(query + b * kD + qq * 128);
        const float4* br = (const float4*)(shB + qq * 128);
        float at = 0.f, aq = 0.f;
        #pragma unroll
        for (int i = 0; i < 32; ++i) {
            float4 w = wr[i]; float4 bb = br[i]; float4 qv = qr[i];
            at += w.x*bb.x + w.y*bb.y + w.z*bb.z + w.w*bb.w;
            aq += w.x*qv.x + w.y*qv.y + w.z*qv.z + w.w*qv.w;
        }
        redT[qq][jj] = at; redQ[qq][jj] = aq;
    }
    __syncthreads();
    if (t < kBD) {
        float tv = redT[0][t] + redT[1][t] + redT[2][t] + redT[3][t] + (float)kN * buq[t];
        float qv = redQ[0][t] + redQ[1][t] + redQ[2][t] + redQ[3][t] + buq[t];
        shMs[t] = tv * qv;
    }
    __syncthreads();

    float lsum = 0.f, lsq = 0.f;
    for (int d = t; d < kD; d += 256) {
        const float4* wr = (const float4*)(Wue + d * kBD);
        float acc = 0.f;
        #pragma unroll
        for (int q4 = 0; q4 < 16; ++q4) {
            float4 w = wr[q4];
            acc += w.x * shMs[q4*4+0] + w.y * shMs[q4*4+1]
                 + w.z * shMs[q4*4+2] + w.w * shMs[q4*4+3];
        }
        float ret = (acc + (float)kN * bue[d]) * (1.0f / 64.0f);
        shN[d] = ret;
        lsum += ret; lsq += ret * ret;
    }
    #pragma unroll
    for (int m = 1; m < 64; m <<= 1) {
        lsum += __shfl_xor(lsum, m);
        lsq  += __shfl_xor(lsq, m);
    }
    if ((t & 63) == 0) { redLN[t >> 6] = lsum; redLN[4 + (t >> 6)] = lsq; }
    __syncthreads();
    if (t == 0) {
        float s0 = redLN[0] + redLN[1] + redLN[2] + redLN[3];
        float s1 = redLN[4] + redLN[5] + redLN[6] + redLN[7];
        float mu = s0 / (float)kD;
        float var = s1 / (float)kD - mu * mu;
        s_mu = mu;
        s_rs = rsqrtf(var + 1e-5f);
    }
    __syncthreads();
    {
        float mu = s_mu, rs = s_rs;
        for (int d = t; d < kD; d += 256)
            shN[d] = (shN[d] - mu) * rs * ln_g[d] + ln_b[d];
    }
    __syncthreads();

    {
        const int d = s * 64 + (t >> 2);
        const int q = t & 3;
        const float4* wr = (const float4*)(Wo + d * kD + q * 128);
        const float4* nr = (const float4*)(shN + q * 128);
        float acc = 0.f;
        #pragma unroll
        for (int i = 0; i < 32; ++i) {
            float4 w = wr[i]; float4 nv = nr[i];
            acc += w.x*nv.x + w.y*nv.y + w.z*nv.z + w.w*nv.w;
        }
        acc += __shfl_xor(acc, 1);
        acc += __shfl_xor(acc, 2);
        if (q == 0) out[b * kD + d] = acc + bo[d];
    }
}

extern "C" void kernel_launch(void* const* d_in, const int* in_sizes, int n_in,
                              void* d_out, int out_size, void* d_ws, size_t ws_size,
                              hipStream_t stream) {
    const float* keys   = (const float*)d_in[0];
    const float* values = (const float*)d_in[1];
    const float* query  = (const float*)d_in[2];
    const float* Wbk    = (const float*)d_in[3];
    const float* bbk    = (const float*)d_in[4];
    const float* Wbv    = (const float*)d_in[5];
    const float* bbv    = (const float*)d_in[6];
    const float* Wbc    = (const float*)d_in[7];
    const float* bbc    = (const float*)d_in[8];
    const float* Wuq    = (const float*)d_in[9];
    const float* buq    = (const float*)d_in[10];
    const float* Wue    = (const float*)d_in[11];
    const float* bue    = (const float*)d_in[12];
    const float* ln_g   = (const float*)d_in[13];
    const float* ln_b   = (const float*)d_in[14];
    const float* Wo     = (const float*)d_in[15];
    const float* bo     = (const float*)d_in[16];

    // ws layout: S (2 KB) | wsk (64 KB) | wsv (64 KB) | kp bf16 (4.2 MB) | vp bf16 (4.2 MB)
    float*  Sacc = (float*)d_ws;
    __bf16* wsk  = (__bf16*)((char*)d_ws + 2048);
    __bf16* wsv  = wsk + kBD * kD;
    __bf16* kp   = wsv + kBD * kD;
    __bf16* vp   = kp + (size_t)kB * kN * kBD;
    float*  out  = (float*)d_out;

    lbm_prep<<<dim3(33), dim3(256), 0, stream>>>(Wbk, Wbv, wsk, wsv, Sacc);
    lbm_proj<<<dim3(512), dim3(1024), 0, stream>>>(keys, values, wsk, wsv,
                                                   bbk, bbv, kp, vp);
    lbm_comb<<<dim3(512), dim3(256), 0, stream>>>(kp, vp, Sacc);
    lbm_tail<<<dim3(kB * 8), dim3(256), 0, stream>>>(Sacc, query, Wbc, bbc, Wuq, buq,
                                                     Wue, bue, ln_g, ln_b, Wo, bo, out);
}

// Round 21
// 51.813 us; speedup vs baseline: 1.1771x; 1.1771x over previous
//
#include <hip/hip_runtime.h>
#include <hip/hip_bf16.h>

typedef __bf16 bf16x8 __attribute__((ext_vector_type(8)));
typedef __bf16 bf16x4 __attribute__((ext_vector_type(4)));
typedef __bf16 bf16x2 __attribute__((ext_vector_type(2)));
typedef float  f32x4  __attribute__((ext_vector_type(4)));
typedef float  f32x2  __attribute__((ext_vector_type(2)));

constexpr int kD  = 512;
constexpr int kBD = 64;
constexpr int kN  = 4096;
constexpr int kB  = 8;

// Prep: Wbk/Wbv fp32 -> bf16 ws images (blocks 0..31); block 32 zeroes S.
__global__ __launch_bounds__(256)
void lbm_prep(const float* __restrict__ Wbk, const float* __restrict__ Wbv,
              __bf16* __restrict__ wsk, __bf16* __restrict__ wsv,
              float* __restrict__ S)
{
    const int bid = blockIdx.x, t = threadIdx.x;
    if (bid < 32) {
        int i = (bid * 256 + t) * 4;
        float4 a = *(const float4*)(Wbk + i);
        float4 b = *(const float4*)(Wbv + i);
        bf16x4 ka, vb;
        ka[0]=(__bf16)a.x; ka[1]=(__bf16)a.y; ka[2]=(__bf16)a.z; ka[3]=(__bf16)a.w;
        vb[0]=(__bf16)b.x; vb[1]=(__bf16)b.y; vb[2]=(__bf16)b.z; vb[3]=(__bf16)b.w;
        *(bf16x4*)(wsk + i) = ka;
        *(bf16x4*)(wsv + i) = vb;
    } else {
        S[t * 2] = 0.f; S[t * 2 + 1] = 0.f;
    }
}

// S[b,j] = sum_n (keys.Wbk + bbk)_j * (values.Wbv + bbv)_j
//
// R14 (best total measured: 52.2 us, refcheck'd): K/V fused, both weight
// images staged once per block (128 KB LDS), 4 row-tiles per block, 256
// blocks x 1024 thr. Probe-shaped 8 B/thread contiguous loads, 3-deep
// counted-vmcnt pipeline (never drains), lgkmcnt-only barriers, K/V
// role-split waves with in-LDS K-publish / V-combine per tile.
__global__ __launch_bounds__(1024, 4)
void lbm_bind(const float* __restrict__ keys, const float* __restrict__ values,
              const __bf16* __restrict__ wsk, const __bf16* __restrict__ wsv,
              const float* __restrict__ bbk,  const float* __restrict__ bbv,
              float* __restrict__ S)
{
    __shared__ __align__(16) __bf16 ldsW[2][kBD * kD];    // both weight sets, 128 KB
    __shared__ __align__(16) __bf16 ldsD[2][2][32 * 64];  // [arr][buf] data, 16 KB
    __shared__ __align__(16) f32x4  red[8 * 64];          // K-proj publish, 8 KB

    const int tid = threadIdx.x;
    const int w    = tid >> 6;
    const int ln   = tid & 63;
    const int l15  = ln & 15;
    const int lhi  = ln >> 4;
    const int sw7  = l15 & 7;
    const int arr  = w & 1;          // 0 = K-projection wave, 1 = V-projection wave
    const int role = w >> 1;         // 0..7 = chunk*4 + jt
    const int chunk = role >> 2;
    const int jt    = role & 3;

    // XCD-bijective: 256 blocks, 8 XCDs -> 32 contiguous blocks (1 batch) each
    const int bid   = blockIdx.x;
    const int swz   = (bid & 7) * 32 + (bid >> 3);
    const int rows0 = swz * 128;     // 4 tiles x 32 rows

    // data staging: thread owns 2 floats/phase, contiguous 256B per 32-lane group
    const int srow = tid >> 5;       // 0..31
    const int wel  = srow * 64 + ((((tid & 31) >> 2) ^ (srow & 7)) << 3) + (tid & 3) * 2;

    const float* kb0 = keys   + (size_t)(rows0 + srow) * kD + (tid & 31) * 2;
    const float* vb0 = values + (size_t)(rows0 + srow) * kD + (tid & 31) * 2;
#define TBK(t_) (kb0 + (t_) * (32 * kD))
#define TBV(t_) (vb0 + (t_) * (32 * kD))

#define LOADP(slK, slV, t_, dph_)                                             \
    asm volatile("global_load_dwordx2 %0, %2, off offset:%c4\n\t"             \
                 "global_load_dwordx2 %1, %3, off offset:%c4"                 \
                 : "=v"(slK), "=v"(slV)                                       \
                 : "v"(TBK(t_)), "v"(TBV(t_)), "i"((dph_) * 256));
#define WAIT2(slK, slV, n_)                                                   \
    asm volatile("s_waitcnt vmcnt(%c2)" : "+v"(slK), "+v"(slV) : "i"(n_));

    f32x2 sK0, sK1, sK2, sV0, sV1, sV2;
#define SLK(q) ((q) % 3 == 0 ? sK0 : ((q) % 3 == 1 ? sK1 : sK2))
#define SLV(q) ((q) % 3 == 0 ? sV0 : ((q) % 3 == 1 ? sV1 : sV2))

    // prologue: 3 phases of data in flight FIRST (oldest), then weights
    LOADP(sK0, sV0, 0, 0)
    LOADP(sK1, sV1, 0, 1)
    LOADP(sK2, sV2, 0, 2)

    // stage BOTH weight images -> XOR-swizzled LDS (once per block)
    #pragma unroll
    for (int i = 0; i < 4; ++i) {
        int G = i * 1024 + tid;              // granule16 0..4095
        int j = G >> 6, c = G & 63;
        int dst = j * kD + ((c ^ (j & 7)) << 3);
        *(bf16x8*)&ldsW[0][dst] = *(const bf16x8*)(wsk + G * 8);
        *(bf16x8*)&ldsW[1][dst] = *(const bf16x8*)(wsv + G * 8);
    }
    const float bk = bbk[jt * 16 + l15];
    const float bv = bbv[jt * 16 + l15];

    WAIT2(sK0, sV0, 4)
    {
        bf16x2 tk, tv;
        tk[0] = (__bf16)sK0[0]; tk[1] = (__bf16)sK0[1];
        tv[0] = (__bf16)sV0[0]; tv[1] = (__bf16)sV0[1];
        *(bf16x2*)&ldsD[0][0][wel] = tk;
        *(bf16x2*)&ldsD[1][0][wel] = tv;
    }
    __syncthreads();   // conservative one-time prologue drain

    f32x4 acc = {0.f, 0.f, 0.f, 0.f};   // this wave's projection accumulator
    float sreg = 0.0f;                   // V-waves: combined sum over tiles

    // phase p (0..31): tile = p>>3, d-phase = p&7.
    // [issue p+3] [2 MFMAs from ldsD[arr][p&1]] [wait p+1, cvt+write] [barrier]
    // tile end (p&7==7): publish K-proj, combine on V-waves, reset acc.
#define PHASE(p_, waitn_)                                                     \
    {                                                                         \
        if ((p_) + 3 < 32) { LOADP(SLK((p_)+3), SLV((p_)+3), ((p_)+3) >> 3, ((p_)+3) & 7) } \
        _Pragma("unroll")                                                     \
        for (int ks = 0; ks < 2; ++ks) {                                      \
            bf16x8 af = *(const bf16x8*)&ldsD[arr][(p_) & 1]                  \
                [(chunk * 16 + l15) * 64 + (((ks * 4 + lhi) ^ sw7) << 3)];    \
            bf16x8 wf = *(const bf16x8*)&ldsW[arr]                            \
                [(jt * 16 + l15) * kD + (((((p_) & 7) * 8 + ks * 4 + lhi) ^ sw7) << 3)]; \
            acc = __builtin_amdgcn_mfma_f32_16x16x32_bf16(af, wf, acc, 0, 0, 0); \
        }                                                                     \
        if ((p_) + 1 < 32) {                                                  \
            WAIT2(SLK((p_)+1), SLV((p_)+1), waitn_)                           \
            bf16x2 tk, tv;                                                    \
            tk[0] = (__bf16)SLK((p_)+1)[0]; tk[1] = (__bf16)SLK((p_)+1)[1];   \
            tv[0] = (__bf16)SLV((p_)+1)[0]; tv[1] = (__bf16)SLV((p_)+1)[1];   \
            *(bf16x2*)&ldsD[0][((p_)+1) & 1][wel] = tk;                       \
            *(bf16x2*)&ldsD[1][((p_)+1) & 1][wel] = tv;                       \
        }                                                                     \
        asm volatile("s_waitcnt lgkmcnt(0)" ::: "memory");                    \
        __builtin_amdgcn_s_barrier();                                         \
        if (((p_) & 7) == 7) {                                                \
            if (arr == 0) red[role * 64 + ln] = acc;                          \
            asm volatile("s_waitcnt lgkmcnt(0)" ::: "memory");                \
            __builtin_amdgcn_s_barrier();                                     \
            if (arr == 1) {                                                   \
                f32x4 kk = red[role * 64 + ln];                               \
                _Pragma("unroll")                                             \
                for (int i = 0; i < 4; ++i)                                   \
                    sreg += (kk[i] + bk) * (acc[i] + bv);                     \
            }                                                                 \
            acc[0] = 0.f; acc[1] = 0.f; acc[2] = 0.f; acc[3] = 0.f;           \
        }                                                                     \
    }

    PHASE(0, 4)  PHASE(1, 4)  PHASE(2, 4)  PHASE(3, 4)
    PHASE(4, 4)  PHASE(5, 4)  PHASE(6, 4)  PHASE(7, 4)
    PHASE(8, 4)  PHASE(9, 4)  PHASE(10, 4) PHASE(11, 4)
    PHASE(12, 4) PHASE(13, 4) PHASE(14, 4) PHASE(15, 4)
    PHASE(16, 4) PHASE(17, 4) PHASE(18, 4) PHASE(19, 4)
    PHASE(20, 4) PHASE(21, 4) PHASE(22, 4) PHASE(23, 4)
    PHASE(24, 4) PHASE(25, 4) PHASE(26, 4) PHASE(27, 4)
    PHASE(28, 4) PHASE(29, 2) PHASE(30, 0) PHASE(31, 0)
#undef PHASE
#undef SLK
#undef SLV
#undef LOADP
#undef WAIT2
#undef TBK
#undef TBV

    // V-waves: reduce sreg over the 4 row-groups and emit S
    if (arr == 1) {
        sreg += __shfl_xor(sreg, 16);
        sreg += __shfl_xor(sreg, 32);
        if (lhi == 0) {
            int bidx = rows0 >> 12;   // / kN
            atomicAdd(&S[bidx * kBD + jt * 16 + l15], sreg);
        }
    }
}

// Fused tail: 64 blocks; each block redundantly computes S->Bsum->ms->ext->LN
// for its batch b, then its 64-wide slice of out = normed.Wo^T + bo.
__global__ __launch_bounds__(256)
void lbm_tail(const float* __restrict__ S,    const float* __restrict__ query,
              const float* __restrict__ Wbc,  const float* __restrict__ bbc,
              const float* __restrict__ Wuq,  const float* __restrict__ buq,
              const float* __restrict__ Wue,  const float* __restrict__ bue,
              const float* __restrict__ ln_g, const float* __restrict__ ln_b,
              const float* __restrict__ Wo,   const float* __restrict__ bo,
              float* __restrict__ out)
{
    const int b = blockIdx.x >> 3;
    const int s = blockIdx.x & 7;
    const int t = threadIdx.x;

    __shared__ float shS[kBD];
    __shared__ float shB[kD];
    __shared__ float shMs[kBD];
    __shared__ float shN[kD];
    __shared__ float redT[4][kBD];
    __shared__ float redQ[4][kBD];
    __shared__ float redLN[8];
    __shared__ float s_mu, s_rs;

    if (t < kBD) shS[t] = S[b * kBD + t];
    __syncthreads();

    for (int d = t; d < kD; d += 256) {
        const float4* wr = (const float4*)(Wbc + d * kBD);
        float acc = 0.f;
        #pragma unroll
        for (int q4 = 0; q4 < 16; ++q4) {
            float4 w = wr[q4];
            acc += w.x * shS[q4*4+0] + w.y * shS[q4*4+1]
                 + w.z * shS[q4*4+2] + w.w * shS[q4*4+3];
        }
        shB[d] = acc + (float)kN * bbc[d];
    }
    __syncthreads();

    {
        const int jj = t & 63, qq = t >> 6;
        const float4* wr = (const float4*)(Wuq + jj * kD + qq * 128);
        const float4* qr = (const float4*)(query + b * kD + qq * 128);
        const float4* br = (const float4*)(shB + qq * 128);
        float at = 0.f, aq = 0.f;
        #pragma unroll
        for (int i = 0; i < 32; ++i) {
            float4 w = wr[i]; float4 bb = br[i]; float4 qv = qr[i];
            at += w.x*bb.x + w.y*bb.y + w.z*bb.z + w.w*bb.w;
            aq += w.x*qv.x + w.y*qv.y + w.z*qv.z + w.w*qv.w;
        }
        redT[qq][jj] = at; redQ[qq][jj] = aq;
    }
    __syncthreads();
    if (t < kBD) {
        float tv = redT[0][t] + redT[1][t] + redT[2][t] + redT[3][t] + (float)kN * buq[t];
        float qv = redQ[0][t] + redQ[1][t] + redQ[2][t] + redQ[3][t] + buq[t];
        shMs[t] = tv * qv;
    }
    __syncthreads();

    float lsum = 0.f, lsq = 0.f;
    for (int d = t; d < kD; d += 256) {
        const float4* wr = (const float4*)(Wue + d * kBD);
        float acc = 0.f;
        #pragma unroll
        for (int q4 = 0; q4 < 16; ++q4) {
            float4 w = wr[q4];
            acc += w.x * shMs[q4*4+0] + w.y * shMs[q4*4+1]
                 + w.z * shMs[q4*4+2] + w.w * shMs[q4*4+3];
        }
        float ret = (acc + (float)kN * bue[d]) * (1.0f / 64.0f);
        shN[d] = ret;
        lsum += ret; lsq += ret * ret;
    }
    #pragma unroll
    for (int m = 1; m < 64; m <<= 1) {
        lsum += __shfl_xor(lsum, m);
        lsq  += __shfl_xor(lsq, m);
    }
    if ((t & 63) == 0) { redLN[t >> 6] = lsum; redLN[4 + (t >> 6)] = lsq; }
    __syncthreads();
    if (t == 0) {
        float s0 = redLN[0] + redLN[1] + redLN[2] + redLN[3];
        float s1 = redLN[4] + redLN[5] + redLN[6] + redLN[7];
        float mu = s0 / (float)kD;
        float var = s1 / (float)kD - mu * mu;
        s_mu = mu;
        s_rs = rsqrtf(var + 1e-5f);
    }
    __syncthreads();
    {
        float mu = s_mu, rs = s_rs;
        for (int d = t; d < kD; d += 256)
            shN[d] = (shN[d] - mu) * rs * ln_g[d] + ln_b[d];
    }
    __syncthreads();

    {
        const int d = s * 64 + (t >> 2);
        const int q = t & 3;
        const float4* wr = (const float4*)(Wo + d * kD + q * 128);
        const float4* nr = (const float4*)(shN + q * 128);
        float acc = 0.f;
        #pragma unroll
        for (int i = 0; i < 32; ++i) {
            float4 w = wr[i]; float4 nv = nr[i];
            acc += w.x*nv.x + w.y*nv.y + w.z*nv.z + w.w*nv.w;
        }
        acc += __shfl_xor(acc, 1);
        acc += __shfl_xor(acc, 2);
        if (q == 0) out[b * kD + d] = acc + bo[d];
    }
}

extern "C" void kernel_launch(void* const* d_in, const int* in_sizes, int n_in,
                              void* d_out, int out_size, void* d_ws, size_t ws_size,
                              hipStream_t stream) {
    const float* keys   = (const float*)d_in[0];
    const float* values = (const float*)d_in[1];
    const float* query  = (const float*)d_in[2];
    const float* Wbk    = (const float*)d_in[3];
    const float* bbk    = (const float*)d_in[4];
    const float* Wbv    = (const float*)d_in[5];
    const float* bbv    = (const float*)d_in[6];
    const float* Wbc    = (const float*)d_in[7];
    const float* bbc    = (const float*)d_in[8];
    const float* Wuq    = (const float*)d_in[9];
    const float* buq    = (const float*)d_in[10];
    const float* Wue    = (const float*)d_in[11];
    const float* bue    = (const float*)d_in[12];
    const float* ln_g   = (const float*)d_in[13];
    const float* ln_b   = (const float*)d_in[14];
    const float* Wo     = (const float*)d_in[15];
    const float* bo     = (const float*)d_in[16];

    // ws layout: S[8][64] f32 (2 KB) | wsk (64 KB) | wsv (64 KB)
    float*  Sacc = (float*)d_ws;
    __bf16* wsk  = (__bf16*)((char*)d_ws + 2048);
    __bf16* wsv  = wsk + kBD * kD;
    float*  out  = (float*)d_out;

    // prep converts weights AND zeroes S (block 32) -- no separate memset node
    lbm_prep<<<dim3(33), dim3(256), 0, stream>>>(Wbk, Wbv, wsk, wsv, Sacc);
    lbm_bind<<<dim3(256), dim3(1024), 0, stream>>>(keys, values, wsk, wsv,
                                                   bbk, bbv, Sacc);
    lbm_tail<<<dim3(kB * 8), dim3(256), 0, stream>>>(Sacc, query, Wbc, bbc, Wuq, buq,
                                                     Wue, bue, ln_g, ln_b, Wo, bo, out);
}